// Round 6
// baseline (1023.931 us; speedup 1.0000x reference)
//
#include <hip/hip_runtime.h>
#include <math.h>

#define BATCH 8192
#define DIM 1024
#define KDIM 512
#define ALPHA_C 0.1f
#define N_ITERS 50
#define ROWS 32
#define ZSH 512

typedef short bf16x8 __attribute__((ext_vector_type(8)));
typedef float f32x4 __attribute__((ext_vector_type(4)));

__device__ __forceinline__ short f2bf(float x) {
  union { float f; unsigned u; } v; v.f = x;
  unsigned r = v.u + 0x7fffu + ((v.u >> 16) & 1u);
  return (short)(r >> 16);
}
__device__ __forceinline__ float bf2f(short s) {
  union { float f; unsigned u; } v;
  v.u = ((unsigned)(unsigned short)s) << 16;
  return v.f;
}

// XOR-swizzled LDS addressing (16B granule): row-major [ROWS][ZSH] shorts
__device__ __forceinline__ int zswz(int row, int col) {
  return row * ZSH + ((((col >> 3) ^ (row & 7)) << 3) | (col & 7));
}
__device__ __forceinline__ int zoff8(int row, int colg) {
  return row * ZSH + ((colg ^ (row & 7)) << 3);
}

// ---------------- K1: C = A^T B  (C: 512x512 fp32; A,B row-stride 512) ----
// 32x32 tile per block, 2x2 per thread, coalesced column access.
__global__ __launch_bounds__(256) void k_mmT(const float* __restrict__ A,
                                             const float* __restrict__ B,
                                             float* __restrict__ C, int K) {
  int tx = (threadIdx.x & 15) * 2;
  int ty = (threadIdx.x >> 4) * 2;
  int a0 = blockIdx.y * 32 + ty;
  int b0 = blockIdx.x * 32 + tx;
  float acc[2][2] = {};
  for (int j = 0; j < K; ++j) {
    float2 av = *(const float2*)&A[(size_t)j * KDIM + a0];
    float2 bv = *(const float2*)&B[(size_t)j * KDIM + b0];
    acc[0][0] += av.x * bv.x;
    acc[0][1] += av.x * bv.y;
    acc[1][0] += av.y * bv.x;
    acc[1][1] += av.y * bv.y;
  }
#pragma unroll
  for (int i = 0; i < 2; ++i)
    *(float2*)&C[(size_t)(a0 + i) * KDIM + b0] =
        make_float2(acc[i][0], acc[i][1]);
}

// ---------------- K2: power iteration on G4 (5 iters) + Rayleigh on G ----
// v <- normalize(G4 v) x5  ==  direction of G^20 * ones  (exact arithmetic),
// then L = v.(G v)/(v.v), step = 1/L. Coalesced symmetric matvecs.
__global__ __launch_bounds__(1024) void k_power4(const float* __restrict__ G4,
                                                 const float* __restrict__ G,
                                                 float* __restrict__ scal) {
  __shared__ float v[KDIM];
  __shared__ float part[1024];
  __shared__ float red[16];
  __shared__ float red2[16];
  __shared__ float stot;
  int tid = threadIdx.x;
  int lane = tid & 63, wid = tid >> 6;
  int col = tid & 511, h = tid >> 9;  // h: j-range half
  if (h == 0) v[col] = 1.0f;
  __syncthreads();

  for (int it = 0; it < 5; ++it) {
    const float* gp = G4 + (size_t)(h * 256) * KDIM + col;
    const float* vp = v + h * 256;
    float a0 = 0, a1 = 0, a2 = 0, a3 = 0;
#pragma unroll 4
    for (int j = 0; j < 256; j += 4) {
      a0 += gp[(size_t)(j + 0) * KDIM] * vp[j + 0];
      a1 += gp[(size_t)(j + 1) * KDIM] * vp[j + 1];
      a2 += gp[(size_t)(j + 2) * KDIM] * vp[j + 2];
      a3 += gp[(size_t)(j + 3) * KDIM] * vp[j + 3];
    }
    part[tid] = (a0 + a1) + (a2 + a3);
    __syncthreads();
    float u = 0.f, s = 0.f;
    if (h == 0) {
      u = part[col] + part[col + 512];
      s = u * u;
    }
#pragma unroll
    for (int off = 32; off; off >>= 1) s += __shfl_xor(s, off);
    if (lane == 0) red[wid] = s;
    __syncthreads();
    if (tid == 0) {
      float t = 0.f;
      for (int i = 0; i < 8; ++i) t += red[i];
      stot = sqrtf(t) + 1e-12f;
    }
    __syncthreads();
    if (h == 0) v[col] = u / stot;
    __syncthreads();
  }

  // Rayleigh on fp32 G
  {
    const float* gp = G + (size_t)(h * 256) * KDIM + col;
    const float* vp = v + h * 256;
    float a0 = 0, a1 = 0, a2 = 0, a3 = 0;
#pragma unroll 4
    for (int j = 0; j < 256; j += 4) {
      a0 += gp[(size_t)(j + 0) * KDIM] * vp[j + 0];
      a1 += gp[(size_t)(j + 1) * KDIM] * vp[j + 1];
      a2 += gp[(size_t)(j + 2) * KDIM] * vp[j + 2];
      a3 += gp[(size_t)(j + 3) * KDIM] * vp[j + 3];
    }
    part[tid] = (a0 + a1) + (a2 + a3);
    __syncthreads();
    float nu = 0.f, de = 0.f;
    if (h == 0) {
      float u = part[col] + part[col + 512];
      nu = v[col] * u;
      de = v[col] * v[col];
    }
#pragma unroll
    for (int off = 32; off; off >>= 1) {
      nu += __shfl_xor(nu, off);
      de += __shfl_xor(de, off);
    }
    if (lane == 0) { red[wid] = nu; red2[wid] = de; }
    __syncthreads();
    if (tid == 0) {
      float n = 0.f, d = 0.f;
      for (int i = 0; i < 8; ++i) { n += red[i]; d += red2[i]; }
      float L = n / (d + 1e-12f);
      float step = 1.0f / L;
      scal[0] = step;
      scal[1] = step * ALPHA_C;
    }
  }
}

// ---------------- K3: pack H = I - step*G (bf16 hi only, B-frag layout) ----
__global__ __launch_bounds__(256) void k_pack_h(const float* __restrict__ G,
                                                const float* __restrict__ scal,
                                                short* __restrict__ Hh) {
  int t = blockIdx.x * 256 + threadIdx.x;  // 512*512
  int k = t >> 9, n = t & 511;
  float step = scal[0];
  float h = ((k == n) ? 1.0f : 0.0f) - step * G[k * KDIM + n];
  int kk = k >> 5, q = (k >> 3) & 3, j = k & 7;
  Hh[((size_t)((kk * 4 + q) * 512 + n)) * 8 + j] = f2bf(h);
}

// Wph[((kk*4+q)*512 + n)*8 + j] = bf16(step*Wd[kk*32+q*8+j][n])
__global__ __launch_bounds__(256) void k_pack_w(const float* __restrict__ Wd,
                                                const float* __restrict__ scal,
                                                short* __restrict__ Wh) {
  int t = blockIdx.x * 256 + threadIdx.x;  // 1024*512
  int k = t >> 9, n = t & 511;
  float w = scal[0] * Wd[k * KDIM + n];
  int kk = k >> 5, q = (k >> 3) & 3, j = k & 7;
  Wh[((size_t)((kk * 4 + q) * 512 + n)) * 8 + j] = f2bf(w);
}

// Wth[((kk*4+q)*1024 + n)*8 + j] = bf16(Wd[n][kk*32+q*8+j])
__global__ __launch_bounds__(256) void k_pack_wt(const float* __restrict__ Wd,
                                                 short* __restrict__ Wh) {
  int t = blockIdx.x * 256 + threadIdx.x;  // 512*1024
  int k = t >> 10, n = t & 1023;
  float w = Wd[n * KDIM + k];
  int kk = k >> 5, q = (k >> 3) & 3, j = k & 7;
  Wh[((size_t)((kk * 4 + q) * 1024 + n)) * 8 + j] = f2bf(w);
}

// ---------------- K4: fused ISTA, 32 rows/block, 256 blocks ----------------
// Z bf16, DOUBLE-BUFFERED in LDS (one barrier/iter). H streamed from L2 with
// it-rotated kk index (defeats LICM hoist-and-spill, R4 pathology).
__global__ __launch_bounds__(512) void k_ista(
    const float* __restrict__ zex, const short* __restrict__ Hh,
    const short* __restrict__ Wph, const short* __restrict__ Wth,
    const float* __restrict__ scal, float* __restrict__ out,
    int* __restrict__ gcnt) {
  __shared__ short Zb[2][ROWS * ZSH];
  int tid = threadIdx.x;
  int lane = tid & 63, wid = tid >> 6;  // 8 waves
  int l15 = lane & 15, lq = lane >> 4;
  int rb = blockIdx.x * ROWS;
  float thr = scal[1];

  // ---------- stage 1: cs = step * X * Wd  (X = permuted zex) ----------
  // hi -> Zb[0], lo -> Zb[1] in ONE staging pass per half.
  f32x4 cs[2][4];
#pragma unroll
  for (int rf = 0; rf < 2; ++rf)
#pragma unroll
    for (int cf = 0; cf < 4; ++cf) cs[rf][cf] = (f32x4){0.f, 0.f, 0.f, 0.f};

  int sr = tid >> 4, sc = tid & 15;  // 512 threads: 32 rows x 16 col-groups
  for (int half = 0; half < 2; ++half) {
    __syncthreads();
    {
      const float* src = &zex[(size_t)(rb + sr) * DIM + sc * 64 + half * 32];
#pragma unroll
      for (int m = 0; m < 32; m += 4) {
        float4 xv = *(const float4*)&src[m];
        float xs[4] = {xv.x, xv.y, xv.z, xv.w};
#pragma unroll
        for (int e = 0; e < 4; ++e) {
          int mm = m + e;
          int dd = ((mm >> 3) << 7) + ((mm & 7) << 4) + sc;
          short hi = f2bf(xs[e]);
          short lo = f2bf(xs[e] - bf2f(hi));
          int zi = zswz(sr, dd);
          Zb[0][zi] = hi;
          Zb[1][zi] = lo;
        }
      }
    }
    __syncthreads();
#pragma unroll 2
    for (int kk = 0; kk < 16; ++kk) {
      int kkg = half * 16 + kk;
      bf16x8 ah[2], al[2];
#pragma unroll
      for (int rf = 0; rf < 2; ++rf) {
        ah[rf] = *(const bf16x8*)&Zb[0][zoff8(rf * 16 + l15, kk * 4 + lq)];
        al[rf] = *(const bf16x8*)&Zb[1][zoff8(rf * 16 + l15, kk * 4 + lq)];
      }
#pragma unroll
      for (int cf = 0; cf < 4; ++cf) {
        int n = wid * 64 + cf * 16 + l15;
        bf16x8 bh = *(const bf16x8*)&Wph[((size_t)((kkg * 4 + lq) * 512 + n)) * 8];
#pragma unroll
        for (int rf = 0; rf < 2; ++rf) {
          cs[rf][cf] = __builtin_amdgcn_mfma_f32_16x16x32_bf16(ah[rf], bh, cs[rf][cf], 0, 0, 0);
          cs[rf][cf] = __builtin_amdgcn_mfma_f32_16x16x32_bf16(al[rf], bh, cs[rf][cf], 0, 0, 0);
        }
      }
    }
  }
  __syncthreads();

  // ---------- init: Z1 = ST(cs) -> Zb[0] ----------
  int cur = 0;
#pragma unroll
  for (int rf = 0; rf < 2; ++rf)
#pragma unroll
    for (int cf = 0; cf < 4; ++cf) {
      int col = wid * 64 + cf * 16 + l15;
#pragma unroll
      for (int e = 0; e < 4; ++e) {
        float pre = cs[rf][cf][e];
        float mag = fmaxf(fabsf(pre) - thr, 0.f);
        float z = (pre >= 0.f) ? mag : -mag;
        int row = rf * 16 + lq * 4 + e;
        Zb[0][zswz(row, col)] = f2bf(z);
      }
    }
  __syncthreads();

  // ---------- iterations 1..49: Z[nxt] = ST(Z[cur]*H + cs); 1 barrier/iter --
#pragma unroll 1
  for (int it = 1; it < N_ITERS; ++it) {
    int rot = it & 15;
    f32x4 acc[2][4];
#pragma unroll
    for (int rf = 0; rf < 2; ++rf)
#pragma unroll
      for (int cf = 0; cf < 4; ++cf) acc[rf][cf] = cs[rf][cf];

#pragma unroll 2
    for (int kk = 0; kk < 16; ++kk) {
      int kkr = (kk + rot) & 15;  // it-dependent: defeats cross-iter LICM
      bf16x8 a[2];
#pragma unroll
      for (int rf = 0; rf < 2; ++rf)
        a[rf] = *(const bf16x8*)&Zb[cur][zoff8(rf * 16 + l15, kkr * 4 + lq)];
#pragma unroll
      for (int cf = 0; cf < 4; ++cf) {
        int n = wid * 64 + cf * 16 + l15;
        bf16x8 bh = *(const bf16x8*)&Hh[((size_t)((kkr * 4 + lq) * 512 + n)) * 8];
#pragma unroll
        for (int rf = 0; rf < 2; ++rf)
          acc[rf][cf] = __builtin_amdgcn_mfma_f32_16x16x32_bf16(a[rf], bh, acc[rf][cf], 0, 0, 0);
      }
    }
    // write next buffer (no conflict with concurrent reads of cur)
#pragma unroll
    for (int rf = 0; rf < 2; ++rf)
#pragma unroll
      for (int cf = 0; cf < 4; ++cf) {
        int col = wid * 64 + cf * 16 + l15;
#pragma unroll
        for (int e = 0; e < 4; ++e) {
          float pre = acc[rf][cf][e];
          float mag = fmaxf(fabsf(pre) - thr, 0.f);
          float z = (pre >= 0.f) ? mag : -mag;
          int row = rf * 16 + lq * 4 + e;
          Zb[cur ^ 1][zswz(row, col)] = f2bf(z);
        }
      }
    cur ^= 1;
    __syncthreads();
  }

  // ---------- sparsity count: scan final Z (swizzle is a bijection) ----------
  int cnt = 0;
#pragma unroll 4
  for (int i = tid; i < ROWS * ZSH; i += 512)
    cnt += (fabsf(bf2f(Zb[cur][i])) > 1e-6f) ? 1 : 0;
#pragma unroll
  for (int off = 32; off; off >>= 1) cnt += __shfl_xor(cnt, off);
  if (lane == 0) atomicAdd(gcnt, cnt);

  // ---------- stage 3: out = Z * Wd^T (1024 cols = 8 waves x 2 passes x 64) ----
#pragma unroll 1
  for (int pass = 0; pass < 2; ++pass) {
    f32x4 o[2][4];
#pragma unroll
    for (int rf = 0; rf < 2; ++rf)
#pragma unroll
      for (int cf = 0; cf < 4; ++cf) o[rf][cf] = (f32x4){0.f, 0.f, 0.f, 0.f};

#pragma unroll 2
    for (int kk = 0; kk < 16; ++kk) {
      bf16x8 a[2];
#pragma unroll
      for (int rf = 0; rf < 2; ++rf)
        a[rf] = *(const bf16x8*)&Zb[cur][zoff8(rf * 16 + l15, kk * 4 + lq)];
#pragma unroll
      for (int cf = 0; cf < 4; ++cf) {
        int n = wid * 128 + pass * 64 + cf * 16 + l15;
        bf16x8 bh = *(const bf16x8*)&Wth[((size_t)((kk * 4 + lq) * 1024 + n)) * 8];
#pragma unroll
        for (int rf = 0; rf < 2; ++rf)
          o[rf][cf] = __builtin_amdgcn_mfma_f32_16x16x32_bf16(a[rf], bh, o[rf][cf], 0, 0, 0);
      }
    }
#pragma unroll
    for (int rf = 0; rf < 2; ++rf)
#pragma unroll
      for (int cf = 0; cf < 4; ++cf) {
        int col = wid * 128 + pass * 64 + cf * 16 + l15;
#pragma unroll
        for (int e = 0; e < 4; ++e) {
          int row = rb + rf * 16 + lq * 4 + e;
          out[(size_t)row * DIM + col] = o[rf][cf][e];
        }
      }
  }
}

// ---------------- K5: finalize sparsity scalar ----------------
__global__ void k_final(const int* __restrict__ gcnt, float* __restrict__ out) {
  out[(size_t)BATCH * DIM] = (float)(*gcnt) / (float)BATCH;
}

extern "C" void kernel_launch(void* const* d_in, const int* in_sizes, int n_in,
                              void* d_out, int out_size, void* d_ws,
                              size_t ws_size, hipStream_t stream) {
  (void)in_sizes; (void)n_in; (void)out_size; (void)ws_size;
  const float* zex = (const float*)d_in[0];
  const float* Wd = (const float*)d_in[1];
  float* out = (float*)d_out;
  char* ws = (char*)d_ws;

  float* G = (float*)ws;                       // 1 MB fp32
  float* scal = (float*)(ws + (1 << 20));      // step, thr
  int* gcnt = (int*)(ws + (1 << 20) + 64);
  short* Hh = (short*)(ws + 2 * (1 << 20));    // 512 KB
  short* Wph = (short*)(ws + 3 * (1 << 20));   // 1 MB
  short* Wth = (short*)(ws + 4 * (1 << 20));   // 1 MB
  float* G2 = (float*)(ws + 5 * (1 << 20));    // 1 MB
  float* G4 = (float*)(ws + 6 * (1 << 20));    // 1 MB

  hipMemsetAsync(gcnt, 0, sizeof(int), stream);
  dim3 gb(16, 16);
  k_mmT<<<gb, 256, 0, stream>>>(Wd, Wd, G, DIM);    // G  = Wd^T Wd
  k_mmT<<<gb, 256, 0, stream>>>(G, G, G2, KDIM);    // G2 = G^2 (G symmetric)
  k_mmT<<<gb, 256, 0, stream>>>(G2, G2, G4, KDIM);  // G4 = G^4
  k_power4<<<1, 1024, 0, stream>>>(G4, G, scal);
  k_pack_h<<<1024, 256, 0, stream>>>(G, scal, Hh);
  k_pack_w<<<2048, 256, 0, stream>>>(Wd, scal, Wph);
  k_pack_wt<<<2048, 256, 0, stream>>>(Wd, Wth);
  k_ista<<<BATCH / ROWS, 512, 0, stream>>>(zex, Hh, Wph, Wth, scal, out, gcnt);
  k_final<<<1, 1, 0, stream>>>(gcnt, out);
}

// Round 8
// 774.444 us; speedup vs baseline: 1.3222x; 1.3222x over previous
//
#include <hip/hip_runtime.h>
#include <math.h>

#define BATCH 8192
#define DIM 1024
#define KDIM 512
#define ALPHA_C 0.1f
#define N_ITERS 50
#define ROWS 64
#define ZSH 512

typedef short bf16x8 __attribute__((ext_vector_type(8)));
typedef float f32x4 __attribute__((ext_vector_type(4)));

__device__ __forceinline__ short f2bf(float x) {
  union { float f; unsigned u; } v; v.f = x;
  unsigned r = v.u + 0x7fffu + ((v.u >> 16) & 1u);
  return (short)(r >> 16);
}
__device__ __forceinline__ float bf2f(short s) {
  union { float f; unsigned u; } v;
  v.u = ((unsigned)(unsigned short)s) << 16;
  return v.f;
}

// XOR-swizzled LDS addressing (16B granule): row-major [ROWS][ZSH] shorts
__device__ __forceinline__ int zswz(int row, int col) {
  return row * ZSH + ((((col >> 3) ^ (row & 7)) << 3) | (col & 7));
}
__device__ __forceinline__ int zoff8(int row, int colg) {
  return row * ZSH + ((colg ^ (row & 7)) << 3);
}

// ---------------- K1: C = scale * A^T B (C: 512x512 fp32), 8-way unrolled --
// scale keeps the G^2 / G^4 / G^8 power chain inside fp32 range
// (lambda_max(G) ~ 3e3 -> G^8 matvec squares overflow fp32 otherwise; R7 bug).
__global__ __launch_bounds__(256) void k_mmT(const float* __restrict__ A,
                                             const float* __restrict__ B,
                                             float* __restrict__ C, int K,
                                             float scale) {
  int tx = (threadIdx.x & 15) * 2;
  int ty = (threadIdx.x >> 4) * 2;
  int a0 = blockIdx.y * 32 + ty;
  int b0 = blockIdx.x * 32 + tx;
  float a00 = 0.f, a01 = 0.f, a10 = 0.f, a11 = 0.f;
  for (int j = 0; j < K; j += 8) {
#pragma unroll
    for (int u = 0; u < 8; ++u) {
      float2 av = *(const float2*)&A[(size_t)(j + u) * KDIM + a0];
      float2 bv = *(const float2*)&B[(size_t)(j + u) * KDIM + b0];
      a00 += av.x * bv.x;
      a01 += av.x * bv.y;
      a10 += av.y * bv.x;
      a11 += av.y * bv.y;
    }
  }
  *(float2*)&C[(size_t)a0 * KDIM + b0] = make_float2(a00 * scale, a01 * scale);
  *(float2*)&C[(size_t)(a0 + 1) * KDIM + b0] =
      make_float2(a10 * scale, a11 * scale);
}

// ---------------- K2: v = dir(G8s·G8s·G4s·1) == dir(G^20·1) (scales cancel);
// L = Rayleigh(G, v). Norm/Rayleigh accumulate in double (overflow-proof).
__global__ __launch_bounds__(1024) void k_power_fast(
    const float* __restrict__ G4, const float* __restrict__ G8,
    const float* __restrict__ G, float* __restrict__ scal) {
  __shared__ float v[KDIM];
  __shared__ float part[1024];
  __shared__ double red[16];
  __shared__ double red2[16];
  __shared__ float stot;
  int tid = threadIdx.x;
  int lane = tid & 63, wid = tid >> 6;
  int col = tid & 511, h = tid >> 9;
  if (h == 0) v[col] = 1.0f;
  __syncthreads();

  const float* mats[3] = {G4, G8, G8};
#pragma unroll
  for (int s = 0; s < 3; ++s) {
    const float* gp = mats[s] + (size_t)(h * 256) * KDIM + col;
    const float* vp = v + h * 256;
    float a0 = 0.f, a1 = 0.f, a2 = 0.f, a3 = 0.f;
#pragma unroll 4
    for (int j = 0; j < 256; j += 4) {
      a0 += gp[(size_t)(j + 0) * KDIM] * vp[j + 0];
      a1 += gp[(size_t)(j + 1) * KDIM] * vp[j + 1];
      a2 += gp[(size_t)(j + 2) * KDIM] * vp[j + 2];
      a3 += gp[(size_t)(j + 3) * KDIM] * vp[j + 3];
    }
    part[tid] = (a0 + a1) + (a2 + a3);
    __syncthreads();
    float u = 0.f;
    double ssq = 0.0;
    if (h == 0) {
      u = part[col] + part[col + 512];
      ssq = (double)u * (double)u;
    }
#pragma unroll
    for (int off = 32; off; off >>= 1) ssq += __shfl_xor(ssq, off);
    if (lane == 0) red[wid] = ssq;
    __syncthreads();
    if (tid == 0) {
      double t = 0.0;
      for (int i = 0; i < 16; ++i) t += red[i];
      stot = (float)(sqrt(t) + 1e-12);
    }
    __syncthreads();
    if (h == 0) v[col] = u / stot;
    __syncthreads();
  }

  // Rayleigh on fp32 G (unscaled)
  {
    const float* gp = G + (size_t)(h * 256) * KDIM + col;
    const float* vp = v + h * 256;
    float a0 = 0.f, a1 = 0.f, a2 = 0.f, a3 = 0.f;
#pragma unroll 4
    for (int j = 0; j < 256; j += 4) {
      a0 += gp[(size_t)(j + 0) * KDIM] * vp[j + 0];
      a1 += gp[(size_t)(j + 1) * KDIM] * vp[j + 1];
      a2 += gp[(size_t)(j + 2) * KDIM] * vp[j + 2];
      a3 += gp[(size_t)(j + 3) * KDIM] * vp[j + 3];
    }
    part[tid] = (a0 + a1) + (a2 + a3);
    __syncthreads();
    double nu = 0.0, de = 0.0;
    if (h == 0) {
      float u = part[col] + part[col + 512];
      nu = (double)v[col] * (double)u;
      de = (double)v[col] * (double)v[col];
    }
#pragma unroll
    for (int off = 32; off; off >>= 1) {
      nu += __shfl_xor(nu, off);
      de += __shfl_xor(de, off);
    }
    if (lane == 0) { red[wid] = nu; red2[wid] = de; }
    __syncthreads();
    if (tid == 0) {
      double n = 0.0, d = 0.0;
      for (int i = 0; i < 16; ++i) { n += red[i]; d += red2[i]; }
      float L = (float)(n / (d + 1e-12));
      float step = 1.0f / L;
      scal[0] = step;
      scal[1] = step * ALPHA_C;
    }
  }
}

// ---------------- K3: pack H = I - step*G (bf16 hi only, B-frag layout) ----
__global__ __launch_bounds__(256) void k_pack_h(const float* __restrict__ G,
                                                const float* __restrict__ scal,
                                                short* __restrict__ Hh) {
  int t = blockIdx.x * 256 + threadIdx.x;  // 512*512
  int k = t >> 9, n = t & 511;
  float step = scal[0];
  float h = ((k == n) ? 1.0f : 0.0f) - step * G[k * KDIM + n];
  int kk = k >> 5, q = (k >> 3) & 3, j = k & 7;
  Hh[((size_t)((kk * 4 + q) * 512 + n)) * 8 + j] = f2bf(h);
}

// Wph[((kk*4+q)*512 + n)*8 + j] = bf16(step*Wd[kk*32+q*8+j][n])
__global__ __launch_bounds__(256) void k_pack_w(const float* __restrict__ Wd,
                                                const float* __restrict__ scal,
                                                short* __restrict__ Wh) {
  int t = blockIdx.x * 256 + threadIdx.x;  // 1024*512
  int k = t >> 9, n = t & 511;
  float w = scal[0] * Wd[k * KDIM + n];
  int kk = k >> 5, q = (k >> 3) & 3, j = k & 7;
  Wh[((size_t)((kk * 4 + q) * 512 + n)) * 8 + j] = f2bf(w);
}

// Wth[((kk*4+q)*1024 + n)*8 + j] = bf16(Wd[n][kk*32+q*8+j])
__global__ __launch_bounds__(256) void k_pack_wt(const float* __restrict__ Wd,
                                                 short* __restrict__ Wh) {
  int t = blockIdx.x * 256 + threadIdx.x;  // 512*1024
  int k = t >> 10, n = t & 1023;
  float w = Wd[n * KDIM + k];
  int kk = k >> 5, q = (k >> 3) & 3, j = k & 7;
  Wh[((size_t)((kk * 4 + q) * 1024 + n)) * 8 + j] = f2bf(w);
}

// ---------------- K4: fused ISTA, 64 rows/block, 128 blocks, 16 waves ------
// Halves aggregate H L2 traffic vs 32-row blocks; 4 waves/SIMD hides L2
// latency. Z single bf16 buffer in LDS (64 KB). it-rotated kk index defeats
// LICM hoist-and-spill (R4 pathology).
__global__ __launch_bounds__(1024) void k_ista(
    const float* __restrict__ zex, const short* __restrict__ Hh,
    const short* __restrict__ Wph, const short* __restrict__ Wth,
    const float* __restrict__ scal, float* __restrict__ out,
    int* __restrict__ gcnt) {
  __shared__ short Zb[ROWS * ZSH];  // 64 KB
  int tid = threadIdx.x;
  int lane = tid & 63, wid = tid >> 6;  // 16 waves
  int wr = wid >> 3, wc = wid & 7;      // 2 x 8 wave grid
  int l15 = lane & 15, lq = lane >> 4;
  int rb = blockIdx.x * ROWS;
  float thr = scal[1];

  // ---------- stage 1: cs = step * X * Wd  (X = permuted zex) ----------
  f32x4 cs[2][4];
#pragma unroll
  for (int rf = 0; rf < 2; ++rf)
#pragma unroll
    for (int cf = 0; cf < 4; ++cf) cs[rf][cf] = (f32x4){0.f, 0.f, 0.f, 0.f};

  int sr = tid >> 4, sc = tid & 15;  // 1024 threads: 64 rows x 16 col-groups
  for (int half = 0; half < 2; ++half) {
    for (int part = 0; part < 2; ++part) {
      __syncthreads();
      {
        const float* src = &zex[(size_t)(rb + sr) * DIM + sc * 64 + half * 32];
#pragma unroll
        for (int m = 0; m < 32; m += 4) {
          float4 xv = *(const float4*)&src[m];
          float xs[4] = {xv.x, xv.y, xv.z, xv.w};
#pragma unroll
          for (int e = 0; e < 4; ++e) {
            int mm = m + e;
            int dd = ((mm >> 3) << 7) + ((mm & 7) << 4) + sc;
            short hi = f2bf(xs[e]);
            short v = part ? f2bf(xs[e] - bf2f(hi)) : hi;
            Zb[zswz(sr, dd)] = v;
          }
        }
      }
      __syncthreads();
#pragma unroll 2
      for (int kk = 0; kk < 16; ++kk) {
        int kkg = half * 16 + kk;
        bf16x8 a[2];
#pragma unroll
        for (int rf = 0; rf < 2; ++rf)
          a[rf] = *(const bf16x8*)&Zb[zoff8(wr * 32 + rf * 16 + l15, kk * 4 + lq)];
#pragma unroll
        for (int cf = 0; cf < 4; ++cf) {
          int n = wc * 64 + cf * 16 + l15;
          bf16x8 bh = *(const bf16x8*)&Wph[((size_t)((kkg * 4 + lq) * 512 + n)) * 8];
#pragma unroll
          for (int rf = 0; rf < 2; ++rf)
            cs[rf][cf] = __builtin_amdgcn_mfma_f32_16x16x32_bf16(a[rf], bh, cs[rf][cf], 0, 0, 0);
        }
      }
    }
  }
  __syncthreads();

  // ---------- init: Z1 = ST(cs) ----------
#pragma unroll
  for (int rf = 0; rf < 2; ++rf)
#pragma unroll
    for (int cf = 0; cf < 4; ++cf) {
      int col = wc * 64 + cf * 16 + l15;
#pragma unroll
      for (int e = 0; e < 4; ++e) {
        float pre = cs[rf][cf][e];
        float mag = fmaxf(fabsf(pre) - thr, 0.f);
        float z = (pre >= 0.f) ? mag : -mag;
        int row = wr * 32 + rf * 16 + lq * 4 + e;
        Zb[zswz(row, col)] = f2bf(z);
      }
    }
  __syncthreads();

  // ---------- iterations 1..49: Z = ST(Z*H + cs) ----------
#pragma unroll 1
  for (int it = 1; it < N_ITERS; ++it) {
    int rot = it & 15;
    f32x4 acc[2][4];
#pragma unroll
    for (int rf = 0; rf < 2; ++rf)
#pragma unroll
      for (int cf = 0; cf < 4; ++cf) acc[rf][cf] = cs[rf][cf];

#pragma unroll 2
    for (int kk = 0; kk < 16; ++kk) {
      int kkr = (kk + rot) & 15;  // it-dependent: defeats cross-iter LICM
      bf16x8 a[2];
#pragma unroll
      for (int rf = 0; rf < 2; ++rf)
        a[rf] = *(const bf16x8*)&Zb[zoff8(wr * 32 + rf * 16 + l15, kkr * 4 + lq)];
#pragma unroll
      for (int cf = 0; cf < 4; ++cf) {
        int n = wc * 64 + cf * 16 + l15;
        bf16x8 bh = *(const bf16x8*)&Hh[((size_t)((kkr * 4 + lq) * 512 + n)) * 8];
#pragma unroll
        for (int rf = 0; rf < 2; ++rf)
          acc[rf][cf] = __builtin_amdgcn_mfma_f32_16x16x32_bf16(a[rf], bh, acc[rf][cf], 0, 0, 0);
      }
    }
    __syncthreads();  // all waves done reading Z
#pragma unroll
    for (int rf = 0; rf < 2; ++rf)
#pragma unroll
      for (int cf = 0; cf < 4; ++cf) {
        int col = wc * 64 + cf * 16 + l15;
#pragma unroll
        for (int e = 0; e < 4; ++e) {
          float pre = acc[rf][cf][e];
          float mag = fmaxf(fabsf(pre) - thr, 0.f);
          float z = (pre >= 0.f) ? mag : -mag;
          int row = wr * 32 + rf * 16 + lq * 4 + e;
          Zb[zswz(row, col)] = f2bf(z);
        }
      }
    __syncthreads();
  }

  // ---------- sparsity count: scan final Z (swizzle is a bijection) ----------
  int cnt = 0;
#pragma unroll 4
  for (int i = tid; i < ROWS * ZSH; i += 1024)
    cnt += (fabsf(bf2f(Zb[i])) > 1e-6f) ? 1 : 0;
#pragma unroll
  for (int off = 32; off; off >>= 1) cnt += __shfl_xor(cnt, off);
  if (lane == 0) atomicAdd(gcnt, cnt);

  // ---------- stage 3: out = Z * Wd^T (1024 cols = 16 waves x 64, rf=4) ----
  {
    f32x4 o[4][4];
#pragma unroll
    for (int rf = 0; rf < 4; ++rf)
#pragma unroll
      for (int cf = 0; cf < 4; ++cf) o[rf][cf] = (f32x4){0.f, 0.f, 0.f, 0.f};

#pragma unroll 2
    for (int kk = 0; kk < 16; ++kk) {
      bf16x8 a[4];
#pragma unroll
      for (int rf = 0; rf < 4; ++rf)
        a[rf] = *(const bf16x8*)&Zb[zoff8(rf * 16 + l15, kk * 4 + lq)];
#pragma unroll
      for (int cf = 0; cf < 4; ++cf) {
        int n = wid * 64 + cf * 16 + l15;
        bf16x8 bh = *(const bf16x8*)&Wth[((size_t)((kk * 4 + lq) * 1024 + n)) * 8];
#pragma unroll
        for (int rf = 0; rf < 4; ++rf)
          o[rf][cf] = __builtin_amdgcn_mfma_f32_16x16x32_bf16(a[rf], bh, o[rf][cf], 0, 0, 0);
      }
    }
#pragma unroll
    for (int rf = 0; rf < 4; ++rf)
#pragma unroll
      for (int cf = 0; cf < 4; ++cf) {
        int col = wid * 64 + cf * 16 + l15;
#pragma unroll
        for (int e = 0; e < 4; ++e) {
          int row = rb + rf * 16 + lq * 4 + e;
          out[(size_t)row * DIM + col] = o[rf][cf][e];
        }
      }
  }
}

// ---------------- K5: finalize sparsity scalar ----------------
__global__ void k_final(const int* __restrict__ gcnt, float* __restrict__ out) {
  out[(size_t)BATCH * DIM] = (float)(*gcnt) / (float)BATCH;
}

extern "C" void kernel_launch(void* const* d_in, const int* in_sizes, int n_in,
                              void* d_out, int out_size, void* d_ws,
                              size_t ws_size, hipStream_t stream) {
  (void)in_sizes; (void)n_in; (void)out_size; (void)ws_size;
  const float* zex = (const float*)d_in[0];
  const float* Wd = (const float*)d_in[1];
  float* out = (float*)d_out;
  char* ws = (char*)d_ws;

  float* G = (float*)ws;                              // 1 MB @ 0
  float* G2 = (float*)(ws + (1 << 20));               // 1 MB @ 1M (scaled)
  float* G4 = (float*)(ws + 2 * (1 << 20));           // 1 MB @ 2M (scaled)
  float* G8 = (float*)(ws + 3 * (1 << 20));           // 1 MB @ 3M (scaled)
  short* Hh = (short*)(ws + 4 * (1 << 20));           // 512 KB @ 4M
  short* Wph = (short*)(ws + 4 * (1 << 20) + (512 << 10));  // 1 MB @ 4.5M
  short* Wth = (short*)(ws + 5 * (1 << 20) + (512 << 10));  // 1 MB @ 5.5M
  float* scal = (float*)(ws + 6 * (1 << 20) + (512 << 10)); // @ 6.5M
  int* gcnt = (int*)(ws + 6 * (1 << 20) + (512 << 10) + 64);

  hipMemsetAsync(gcnt, 0, sizeof(int), stream);
  dim3 gb(16, 16);
  // Power chain scaled by 2^-20 at the first squaring: keeps lambda(G8s)
  // ~5e3 (was lambda(G)^8 ~ 6e27 -> matvec norms overflowed fp32 in R7).
  k_mmT<<<gb, 256, 0, stream>>>(Wd, Wd, G, DIM, 1.0f);          // G = Wd^T Wd
  k_mmT<<<gb, 256, 0, stream>>>(G, G, G2, KDIM, 9.5367431640625e-07f);  // G^2*2^-20
  k_mmT<<<gb, 256, 0, stream>>>(G2, G2, G4, KDIM, 1.0f);        // G^4*2^-40
  k_mmT<<<gb, 256, 0, stream>>>(G4, G4, G8, KDIM, 1.0f);        // G^8*2^-80
  k_power_fast<<<1, 1024, 0, stream>>>(G4, G8, G, scal);
  k_pack_h<<<1024, 256, 0, stream>>>(G, scal, Hh);
  k_pack_w<<<2048, 256, 0, stream>>>(Wd, scal, Wph);
  k_pack_wt<<<2048, 256, 0, stream>>>(Wd, Wth);
  k_ista<<<BATCH / ROWS, 1024, 0, stream>>>(zex, Hh, Wph, Wth, scal, out, gcnt);
  k_final<<<1, 1, 0, stream>>>(gcnt, out);
}

// Round 9
// 543.540 us; speedup vs baseline: 1.8838x; 1.4248x over previous
//
#include <hip/hip_runtime.h>
#include <math.h>

#define BATCH 8192
#define DIM 1024
#define KDIM 512
#define ALPHA_C 0.1f
#define N_ITERS 50
#define ROWS 32
#define ZSH 512

typedef short bf16x8 __attribute__((ext_vector_type(8)));
typedef float f32x4 __attribute__((ext_vector_type(4)));

__device__ __forceinline__ short f2bf(float x) {
  union { float f; unsigned u; } v; v.f = x;
  unsigned r = v.u + 0x7fffu + ((v.u >> 16) & 1u);
  return (short)(r >> 16);
}
__device__ __forceinline__ float bf2f(short s) {
  union { float f; unsigned u; } v;
  v.u = ((unsigned)(unsigned short)s) << 16;
  return v.f;
}

// XOR-swizzled LDS addressing (16B granule): row-major [ROWS][ZSH] shorts
__device__ __forceinline__ int zswz(int row, int col) {
  return row * ZSH + ((((col >> 3) ^ (row & 7)) << 3) | (col & 7));
}
__device__ __forceinline__ int zoff8(int row, int colg) {
  return row * ZSH + ((colg ^ (row & 7)) << 3);
}

// ---------------- K1: C = scale * A^T B (C: 512x512 fp32), 8-way unrolled --
__global__ __launch_bounds__(256) void k_mmT(const float* __restrict__ A,
                                             const float* __restrict__ B,
                                             float* __restrict__ C, int K,
                                             float scale) {
  int tx = (threadIdx.x & 15) * 2;
  int ty = (threadIdx.x >> 4) * 2;
  int a0 = blockIdx.y * 32 + ty;
  int b0 = blockIdx.x * 32 + tx;
  float a00 = 0.f, a01 = 0.f, a10 = 0.f, a11 = 0.f;
  for (int j = 0; j < K; j += 8) {
#pragma unroll
    for (int u = 0; u < 8; ++u) {
      float2 av = *(const float2*)&A[(size_t)(j + u) * KDIM + a0];
      float2 bv = *(const float2*)&B[(size_t)(j + u) * KDIM + b0];
      a00 += av.x * bv.x;
      a01 += av.x * bv.y;
      a10 += av.y * bv.x;
      a11 += av.y * bv.y;
    }
  }
  *(float2*)&C[(size_t)a0 * KDIM + b0] = make_float2(a00 * scale, a01 * scale);
  *(float2*)&C[(size_t)(a0 + 1) * KDIM + b0] =
      make_float2(a10 * scale, a11 * scale);
}

// ---------------- K2: v = dir(G8s·G8s·G4s·1) == dir(G^20·1) (scales cancel);
// L = Rayleigh(G, v). Norm/Rayleigh accumulate in double (overflow-proof).
__global__ __launch_bounds__(1024) void k_power_fast(
    const float* __restrict__ G4, const float* __restrict__ G8,
    const float* __restrict__ G, float* __restrict__ scal) {
  __shared__ float v[KDIM];
  __shared__ float part[1024];
  __shared__ double red[16];
  __shared__ double red2[16];
  __shared__ float stot;
  int tid = threadIdx.x;
  int lane = tid & 63, wid = tid >> 6;
  int col = tid & 511, h = tid >> 9;
  if (h == 0) v[col] = 1.0f;
  __syncthreads();

  const float* mats[3] = {G4, G8, G8};
#pragma unroll
  for (int s = 0; s < 3; ++s) {
    const float* gp = mats[s] + (size_t)(h * 256) * KDIM + col;
    const float* vp = v + h * 256;
    float a0 = 0.f, a1 = 0.f, a2 = 0.f, a3 = 0.f;
#pragma unroll 4
    for (int j = 0; j < 256; j += 4) {
      a0 += gp[(size_t)(j + 0) * KDIM] * vp[j + 0];
      a1 += gp[(size_t)(j + 1) * KDIM] * vp[j + 1];
      a2 += gp[(size_t)(j + 2) * KDIM] * vp[j + 2];
      a3 += gp[(size_t)(j + 3) * KDIM] * vp[j + 3];
    }
    part[tid] = (a0 + a1) + (a2 + a3);
    __syncthreads();
    float u = 0.f;
    double ssq = 0.0;
    if (h == 0) {
      u = part[col] + part[col + 512];
      ssq = (double)u * (double)u;
    }
#pragma unroll
    for (int off = 32; off; off >>= 1) ssq += __shfl_xor(ssq, off);
    if (lane == 0) red[wid] = ssq;
    __syncthreads();
    if (tid == 0) {
      double t = 0.0;
      for (int i = 0; i < 16; ++i) t += red[i];
      stot = (float)(sqrt(t) + 1e-12);
    }
    __syncthreads();
    if (h == 0) v[col] = u / stot;
    __syncthreads();
  }

  // Rayleigh on fp32 G (unscaled)
  {
    const float* gp = G + (size_t)(h * 256) * KDIM + col;
    const float* vp = v + h * 256;
    float a0 = 0.f, a1 = 0.f, a2 = 0.f, a3 = 0.f;
#pragma unroll 4
    for (int j = 0; j < 256; j += 4) {
      a0 += gp[(size_t)(j + 0) * KDIM] * vp[j + 0];
      a1 += gp[(size_t)(j + 1) * KDIM] * vp[j + 1];
      a2 += gp[(size_t)(j + 2) * KDIM] * vp[j + 2];
      a3 += gp[(size_t)(j + 3) * KDIM] * vp[j + 3];
    }
    part[tid] = (a0 + a1) + (a2 + a3);
    __syncthreads();
    double nu = 0.0, de = 0.0;
    if (h == 0) {
      float u = part[col] + part[col + 512];
      nu = (double)v[col] * (double)u;
      de = (double)v[col] * (double)v[col];
    }
#pragma unroll
    for (int off = 32; off; off >>= 1) {
      nu += __shfl_xor(nu, off);
      de += __shfl_xor(de, off);
    }
    if (lane == 0) { red[wid] = nu; red2[wid] = de; }
    __syncthreads();
    if (tid == 0) {
      double n = 0.0, d = 0.0;
      for (int i = 0; i < 16; ++i) { n += red[i]; d += red2[i]; }
      float L = (float)(n / (d + 1e-12));
      float step = 1.0f / L;
      scal[0] = step;
      scal[1] = step * ALPHA_C;
    }
  }
}

// ---------------- K3: pack H = I - step*G (bf16 hi only, B-frag layout) ----
__global__ __launch_bounds__(256) void k_pack_h(const float* __restrict__ G,
                                                const float* __restrict__ scal,
                                                short* __restrict__ Hh) {
  int t = blockIdx.x * 256 + threadIdx.x;  // 512*512
  int k = t >> 9, n = t & 511;
  float step = scal[0];
  float h = ((k == n) ? 1.0f : 0.0f) - step * G[k * KDIM + n];
  int kk = k >> 5, q = (k >> 3) & 3, j = k & 7;
  Hh[((size_t)((kk * 4 + q) * 512 + n)) * 8 + j] = f2bf(h);
}

// Wph[((kk*4+q)*512 + n)*8 + j] = bf16(step*Wd[kk*32+q*8+j][n])
__global__ __launch_bounds__(256) void k_pack_w(const float* __restrict__ Wd,
                                                const float* __restrict__ scal,
                                                short* __restrict__ Wh) {
  int t = blockIdx.x * 256 + threadIdx.x;  // 1024*512
  int k = t >> 9, n = t & 511;
  float w = scal[0] * Wd[k * KDIM + n];
  int kk = k >> 5, q = (k >> 3) & 3, j = k & 7;
  Wh[((size_t)((kk * 4 + q) * 512 + n)) * 8 + j] = f2bf(w);
}

// Wth[((kk*4+q)*1024 + n)*8 + j] = bf16(Wd[n][kk*32+q*8+j])
__global__ __launch_bounds__(256) void k_pack_wt(const float* __restrict__ Wd,
                                                 short* __restrict__ Wh) {
  int t = blockIdx.x * 256 + threadIdx.x;  // 512*1024
  int k = t >> 10, n = t & 1023;
  float w = Wd[n * KDIM + k];
  int kk = k >> 5, q = (k >> 3) & 3, j = k & 7;
  Wh[((size_t)((kk * 4 + q) * 1024 + n)) * 8 + j] = f2bf(w);
}

// ---------------- K4: fused ISTA: 32 rows/block, 256 blocks, 16 waves ------
// Full chip (256 blocks) + minimal per-block H traffic (32 rows -> 512 KB/iter)
// + 4 waves/SIMD latency hiding (R8 lesson). Wave grid 1x16: each wave owns a
// 32-row x 32-col tile (rf=2, cf=2) -> no duplicate B-loads across waves.
// it-rotated kk defeats LICM hoist-and-spill (R4 pathology).
__global__ __launch_bounds__(1024) void k_ista(
    const float* __restrict__ zex, const short* __restrict__ Hh,
    const short* __restrict__ Wph, const short* __restrict__ Wth,
    const float* __restrict__ scal, float* __restrict__ out,
    int* __restrict__ gcnt) {
  __shared__ short Zb[ROWS * ZSH];  // 32 KB (Z / X-hi)
  __shared__ short Zc[ROWS * ZSH];  // 32 KB (X-lo, stage 1 only)
  int tid = threadIdx.x;
  int lane = tid & 63, wid = tid >> 6;  // 16 waves, each 32 cols
  int l15 = lane & 15, lq = lane >> 4;
  int rb = blockIdx.x * ROWS;
  float thr = scal[1];

  // ---------- stage 1: cs = step * X * Wd  (X = permuted zex) ----------
  // hi -> Zb, lo -> Zc in ONE staging pass per 512-col half.
  f32x4 cs[2][2];
#pragma unroll
  for (int rf = 0; rf < 2; ++rf)
#pragma unroll
    for (int cf = 0; cf < 2; ++cf) cs[rf][cf] = (f32x4){0.f, 0.f, 0.f, 0.f};

  // staging map: 1024 threads = 32 rows x 16 col-groups x 2 m-phases
  int sr = tid >> 5;            // row 0..31
  int sc = (tid & 31) >> 1;     // col-group 0..15
  int ph = tid & 1;             // m-phase 0..1 (16 floats each)
  for (int half = 0; half < 2; ++half) {
    __syncthreads();
    {
      const float* src =
          &zex[(size_t)(rb + sr) * DIM + sc * 64 + half * 32 + ph * 16];
#pragma unroll
      for (int m = 0; m < 16; m += 4) {
        float4 xv = *(const float4*)&src[m];
        float xs[4] = {xv.x, xv.y, xv.z, xv.w};
#pragma unroll
        for (int e = 0; e < 4; ++e) {
          int mm = ph * 16 + m + e;
          int dd = ((mm >> 3) << 7) + ((mm & 7) << 4) + sc;
          short hi = f2bf(xs[e]);
          short lo = f2bf(xs[e] - bf2f(hi));
          int zi = zswz(sr, dd);
          Zb[zi] = hi;
          Zc[zi] = lo;
        }
      }
    }
    __syncthreads();
#pragma unroll 2
    for (int kk = 0; kk < 16; ++kk) {
      int kkg = half * 16 + kk;
      bf16x8 ah[2], al[2];
#pragma unroll
      for (int rf = 0; rf < 2; ++rf) {
        int zo = zoff8(rf * 16 + l15, kk * 4 + lq);
        ah[rf] = *(const bf16x8*)&Zb[zo];
        al[rf] = *(const bf16x8*)&Zc[zo];
      }
#pragma unroll
      for (int cf = 0; cf < 2; ++cf) {
        int n = wid * 32 + cf * 16 + l15;
        bf16x8 bh = *(const bf16x8*)&Wph[((size_t)((kkg * 4 + lq) * 512 + n)) * 8];
#pragma unroll
        for (int rf = 0; rf < 2; ++rf) {
          cs[rf][cf] = __builtin_amdgcn_mfma_f32_16x16x32_bf16(ah[rf], bh, cs[rf][cf], 0, 0, 0);
          cs[rf][cf] = __builtin_amdgcn_mfma_f32_16x16x32_bf16(al[rf], bh, cs[rf][cf], 0, 0, 0);
        }
      }
    }
  }
  __syncthreads();

  // ---------- init: Z1 = ST(cs) ----------
#pragma unroll
  for (int rf = 0; rf < 2; ++rf)
#pragma unroll
    for (int cf = 0; cf < 2; ++cf) {
      int col = wid * 32 + cf * 16 + l15;
#pragma unroll
      for (int e = 0; e < 4; ++e) {
        float pre = cs[rf][cf][e];
        float mag = fmaxf(fabsf(pre) - thr, 0.f);
        float z = (pre >= 0.f) ? mag : -mag;
        int row = rf * 16 + lq * 4 + e;
        Zb[zswz(row, col)] = f2bf(z);
      }
    }
  __syncthreads();

  // ---------- iterations 1..49: Z = ST(Z*H + cs) ----------
#pragma unroll 1
  for (int it = 1; it < N_ITERS; ++it) {
    int rot = it & 15;
    f32x4 acc[2][2];
#pragma unroll
    for (int rf = 0; rf < 2; ++rf)
#pragma unroll
      for (int cf = 0; cf < 2; ++cf) acc[rf][cf] = cs[rf][cf];

#pragma unroll 2
    for (int kk = 0; kk < 16; ++kk) {
      int kkr = (kk + rot) & 15;  // it-dependent: defeats cross-iter LICM
      bf16x8 a[2];
#pragma unroll
      for (int rf = 0; rf < 2; ++rf)
        a[rf] = *(const bf16x8*)&Zb[zoff8(rf * 16 + l15, kkr * 4 + lq)];
#pragma unroll
      for (int cf = 0; cf < 2; ++cf) {
        int n = wid * 32 + cf * 16 + l15;
        bf16x8 bh = *(const bf16x8*)&Hh[((size_t)((kkr * 4 + lq) * 512 + n)) * 8];
#pragma unroll
        for (int rf = 0; rf < 2; ++rf)
          acc[rf][cf] = __builtin_amdgcn_mfma_f32_16x16x32_bf16(a[rf], bh, acc[rf][cf], 0, 0, 0);
      }
    }
    __syncthreads();  // all waves done reading Z
#pragma unroll
    for (int rf = 0; rf < 2; ++rf)
#pragma unroll
      for (int cf = 0; cf < 2; ++cf) {
        int col = wid * 32 + cf * 16 + l15;
#pragma unroll
        for (int e = 0; e < 4; ++e) {
          float pre = acc[rf][cf][e];
          float mag = fmaxf(fabsf(pre) - thr, 0.f);
          float z = (pre >= 0.f) ? mag : -mag;
          int row = rf * 16 + lq * 4 + e;
          Zb[zswz(row, col)] = f2bf(z);
        }
      }
    __syncthreads();
  }

  // ---------- sparsity count: scan final Z (swizzle is a bijection) ----------
  int cnt = 0;
#pragma unroll 4
  for (int i = tid; i < ROWS * ZSH; i += 1024)
    cnt += (fabsf(bf2f(Zb[i])) > 1e-6f) ? 1 : 0;
#pragma unroll
  for (int off = 32; off; off >>= 1) cnt += __shfl_xor(cnt, off);
  if (lane == 0) atomicAdd(gcnt, cnt);

  // ---------- stage 3: out = Z * Wd^T (1024 cols = 16 waves x 64) ----------
  {
    f32x4 o[2][4];
#pragma unroll
    for (int rf = 0; rf < 2; ++rf)
#pragma unroll
      for (int cf = 0; cf < 4; ++cf) o[rf][cf] = (f32x4){0.f, 0.f, 0.f, 0.f};

#pragma unroll 2
    for (int kk = 0; kk < 16; ++kk) {
      bf16x8 a[2];
#pragma unroll
      for (int rf = 0; rf < 2; ++rf)
        a[rf] = *(const bf16x8*)&Zb[zoff8(rf * 16 + l15, kk * 4 + lq)];
#pragma unroll
      for (int cf = 0; cf < 4; ++cf) {
        int n = wid * 64 + cf * 16 + l15;
        bf16x8 bh = *(const bf16x8*)&Wth[((size_t)((kk * 4 + lq) * 1024 + n)) * 8];
#pragma unroll
        for (int rf = 0; rf < 2; ++rf)
          o[rf][cf] = __builtin_amdgcn_mfma_f32_16x16x32_bf16(a[rf], bh, o[rf][cf], 0, 0, 0);
      }
    }
#pragma unroll
    for (int rf = 0; rf < 2; ++rf)
#pragma unroll
      for (int cf = 0; cf < 4; ++cf) {
        int col = wid * 64 + cf * 16 + l15;
#pragma unroll
        for (int e = 0; e < 4; ++e) {
          int row = rb + rf * 16 + lq * 4 + e;
          out[(size_t)row * DIM + col] = o[rf][cf][e];
        }
      }
  }
}

// ---------------- K5: finalize sparsity scalar ----------------
__global__ void k_final(const int* __restrict__ gcnt, float* __restrict__ out) {
  out[(size_t)BATCH * DIM] = (float)(*gcnt) / (float)BATCH;
}

extern "C" void kernel_launch(void* const* d_in, const int* in_sizes, int n_in,
                              void* d_out, int out_size, void* d_ws,
                              size_t ws_size, hipStream_t stream) {
  (void)in_sizes; (void)n_in; (void)out_size; (void)ws_size;
  const float* zex = (const float*)d_in[0];
  const float* Wd = (const float*)d_in[1];
  float* out = (float*)d_out;
  char* ws = (char*)d_ws;

  float* G = (float*)ws;                              // 1 MB @ 0
  float* G2 = (float*)(ws + (1 << 20));               // 1 MB @ 1M (scaled)
  float* G4 = (float*)(ws + 2 * (1 << 20));           // 1 MB @ 2M (scaled)
  float* G8 = (float*)(ws + 3 * (1 << 20));           // 1 MB @ 3M (scaled)
  short* Hh = (short*)(ws + 4 * (1 << 20));           // 512 KB @ 4M
  short* Wph = (short*)(ws + 4 * (1 << 20) + (512 << 10));  // 1 MB @ 4.5M
  short* Wth = (short*)(ws + 5 * (1 << 20) + (512 << 10));  // 1 MB @ 5.5M
  float* scal = (float*)(ws + 6 * (1 << 20) + (512 << 10)); // @ 6.5M
  int* gcnt = (int*)(ws + 6 * (1 << 20) + (512 << 10) + 64);

  hipMemsetAsync(gcnt, 0, sizeof(int), stream);
  dim3 gb(16, 16);
  // Power chain scaled by 2^-20 at the first squaring (R7 overflow fix).
  k_mmT<<<gb, 256, 0, stream>>>(Wd, Wd, G, DIM, 1.0f);          // G = Wd^T Wd
  k_mmT<<<gb, 256, 0, stream>>>(G, G, G2, KDIM, 9.5367431640625e-07f);  // G^2*2^-20
  k_mmT<<<gb, 256, 0, stream>>>(G2, G2, G4, KDIM, 1.0f);        // G^4*2^-40
  k_mmT<<<gb, 256, 0, stream>>>(G4, G4, G8, KDIM, 1.0f);        // G^8*2^-80
  k_power_fast<<<1, 1024, 0, stream>>>(G4, G8, G, scal);
  k_pack_h<<<1024, 256, 0, stream>>>(G, scal, Hh);
  k_pack_w<<<2048, 256, 0, stream>>>(Wd, scal, Wph);
  k_pack_wt<<<2048, 256, 0, stream>>>(Wd, Wth);
  k_ista<<<BATCH / ROWS, 1024, 0, stream>>>(zex, Hh, Wph, Wth, scal, out, gcnt);
  k_final<<<1, 1, 0, stream>>>(gcnt, out);
}